// Round 5
// baseline (179.499 us; speedup 1.0000x reference)
//
#include <hip/hip_runtime.h>

// Sinkhorn fixed-point for fermionic canonical ensembles.
// B=2048 systems, P=64 orbitals, N_PART=32, n_iters from d_in[2].
//
// Strategy (R4): ACCURACY-FIRST faithful fp32. R0/R2/R3 showed the 20-iter
// map amplifies per-op rounding noise ~1e3-1e4x, with +-3x codegen-draw
// variance (R0 7.8e-3 vs op-identical R3 2.3e-2). So instead of matching a
// lucky draw, lower the intrinsic noise floor ~15x:
//   * contract(off): mul+sub never fused -- matches the reference's op list
//   * true IEEE '/' on every reference-visible divide (no fastrcp)
//   * exp: arg = round(-beta*k*eps) (numpy's rounding), then Cody-Waite
//     corrected v_exp_f32 => <=1.5 ulp (R0's __expf was ~27 ulp at |arg|~27,
//     the dominant noise source)
//   * log: v_log_f32 + split-ln2 (~1.5 ulp)
//   * reductions replicate numpy pairwise_sum order (8 strided accs + tree)
//   * all cross-lane data via register shuffles: NO LDS, NO barriers
//     (avoids R1's compiler-reordered LDS RAW hazard class entirely)
// Q recursion stays lane-pipelined (lane l carries M=l+1, 31 steps).

#pragma clang fp contract(off)

#define NPART 32
#define PORB  64

// float(log2(e)) and residual; float(ln2) and residual
#define L2E_HI 1.44269502162933349609375f
#define L2E_LO 1.9259629911266175e-08f
#define LN2_HI 0.69314718246459960938f
#define LN2_LO -1.9046542121259175e-09f
#define LN2F   0.6931471805599453f

__device__ __forceinline__ float readlane_f(float v, int srclane) {
    return __int_as_float(__builtin_amdgcn_readlane(__float_as_int(v), srclane));
}

// e^arg = 2^(arg*log2e), arg already rounded like the reference's product.
// Cody-Waite: p = fl(arg*L2E_HI); residual c = (arg*L2E_HI - p) + arg*L2E_LO
// folded as first-order correction. |c| <= ~3e-6 so (c*ln2)^2 is negligible.
__device__ __forceinline__ float exp_acc(float arg) {
    float p    = arg * L2E_HI;
    float perr = fmaf(arg, L2E_HI, -p);        // exact residual of the product
    float c    = fmaf(arg, L2E_LO, perr);
    float e0   = __builtin_amdgcn_exp2f(p);    // v_exp_f32, ~1 ulp on result
    return fmaf(e0, c * LN2F, e0);             // e0*(1 + c*ln2)
}

// ln(x) = log2(x)*ln2 with split constant (~1.5 ulp)
__device__ __forceinline__ float ln_acc(float x) {
    float l2 = __log2f(x);                     // v_log_f32, ~1 ulp
    float p  = l2 * LN2_HI;
    float e  = fmaf(l2, LN2_HI, -p);
    return p + fmaf(l2, LN2_LO, e);
}

// numpy pairwise_sum order for 64 elements (n<=128 path):
//   r[j] = v[j] + v[j+8] + ... + v[j+56]  (sequential), j=0..7
//   T = ((r0+r1)+(r2+r3)) + ((r4+r5)+(r6+r7))
// Lanes 8..63 compute rotated junk partials; only lanes 0..7 are read.
__device__ __forceinline__ float pairwise_np(float v, int lane) {
    float c = v;
    #pragma unroll
    for (int i = 1; i < 8; ++i)
        c = c + __shfl(v, (lane + 8 * i) & 63);
    float r0 = readlane_f(c, 0), r1 = readlane_f(c, 1);
    float r2 = readlane_f(c, 2), r3 = readlane_f(c, 3);
    float r4 = readlane_f(c, 4), r5 = readlane_f(c, 5);
    float r6 = readlane_f(c, 6), r7 = readlane_f(c, 7);
    return ((r0 + r1) + (r2 + r3)) + ((r4 + r5) + (r6 + r7));
}

__global__ __launch_bounds__(PORB, 1) void sinkhorn_kernel(
    const float* __restrict__ n_in,
    const float* __restrict__ beta_ptr,
    const int*   __restrict__ iters_ptr,
    float*       __restrict__ out)
{
    const int b    = blockIdx.x;
    const int lane = threadIdx.x;               // orbital index p
    const float beta    = beta_ptr[0];
    const int   n_iters = iters_ptr[0];
    const float nb      = -beta;                // exact negate

    const float n_p = n_in[b * PORB + lane];

    // ---- setup: nn = n/sum(n)*N, snn, ratio, eps0 (faithful op order) ----
    const float srt = pairwise_np(n_p, lane);
    const float nn  = (n_p / srt) * (float)NPART;
    const float snn = pairwise_np(nn, lane);
    const float ratio_nn = nn / (1.0f - nn);
    float eps = (-ln_acc(ratio_nn)) / beta;     // eps_GC_guess

    // per-lane constants for the C_k block
    const float kf    = (float)((lane & 31) + 1);
    const float mk    = nb * kf;                // round(-beta*k), numpy's order
    const int   jbase = (lane & 32) >> 3;       // half0 -> r0..r3, half1 -> r4..r7

    for (int it = 0; it < n_iters; ++it) {
        // ---- C_{k} = sum_p exp(-beta*k*eps_p), numpy pairwise order ----
        // lane (k,half) builds 4 of numpy's 8 accumulators, 8 terms each.
        float acc[4];
        #pragma unroll
        for (int jj = 0; jj < 4; ++jj) {
            #pragma unroll
            for (int i = 0; i < 8; ++i) {
                const int idx = jbase + jj + 8 * i;      // orbital index
                const float ej  = __shfl(eps, idx);      // register gather
                const float arg = mk * ej;               // numpy's single rounding
                const float v   = exp_acc(arg);
                acc[jj] = (i == 0) ? v : (acc[jj] + v);  // sequential, np order
            }
        }
        float shalf = (acc[0] + acc[1]) + (acc[2] + acc[3]);
        float Cfull = shalf + __shfl_xor(shalf, 32);     // np's final combine
        // lane i in 0..31 holds C[i+1] (mirrored in 32..63)

        const float c1 = readlane_f(Cfull, 0);           // C[1]

        // E_np[i] = C[i+1]/C[i]: true divide (lane0/half1 junk, never read)
        const float prevC = __shfl(Cfull, (lane - 1) & 63);
        const float E     = Cfull / prevC;

        // ---- lane-pipelined Q recursion: lane l carries M=l+1 ----
        // step s: p <- 1 - (E[l+1-s]/Q[s-1])*p, all ops exactly as reference
        float Q[NPART];                                   // wave-uniform values
        Q[0] = c1;
        float p = 1.0f;
        #pragma unroll
        for (int s = 1; s < NPART; ++s) {
            const float Er = __shfl(E, (lane + 1 - s) & 63);
            const float d  = Er / Q[s - 1];               // true divide
            const float m  = d * p;
            p = 1.0f - m;                                 // no contraction
            const float ps = readlane_f(p, s);
            Q[s] = (c1 * ps) / (float)(s + 1);            // C[1]*prev/M
        }

        // ---- aux: per-orbital 32-step recursion, faithful ops ----
        const float x = exp_acc(nb * eps);                // exp(-beta*eps_p)
        float prev = 1.0f, y30 = 0.0f;
        #pragma unroll
        for (int k = 0; k < NPART; ++k) {
            const float d = x / Q[k];                     // true divide
            const float m = d * prev;
            prev = 1.0f - m;
            if (k == NPART - 2) y30 = prev;
        }
        const float Qp1 = prev;                           // ys[N-1]
        const float Qp0 = y30 / Q[NPART - 1];             // ys[N-2]/Q[N-1]

        // ---- update + normalize, faithful op order ----
        const float q_arg   = (ratio_nn * Qp1) / Qp0;
        const float eps_new = (-ln_acc(q_arg)) / beta;

        const float W = pairwise_np(nn * eps_new, lane);  // sum(nn*eps_new)
        eps = eps_new - (W / snn);
    }

    out[b * PORB + lane] = eps;
}

extern "C" void kernel_launch(void* const* d_in, const int* in_sizes, int n_in,
                              void* d_out, int out_size, void* d_ws, size_t ws_size,
                              hipStream_t stream) {
    const float* n_ptr    = (const float*)d_in[0];
    const float* beta_ptr = (const float*)d_in[1];
    const int*   it_ptr   = (const int*)d_in[2];
    float*       out      = (float*)d_out;

    const int B = in_sizes[0] / PORB;   // 2048 systems
    sinkhorn_kernel<<<B, PORB, 0, stream>>>(n_ptr, beta_ptr, it_ptr, out);
}

// Round 6
// 126.278 us; speedup vs baseline: 1.4215x; 1.4215x over previous
//
#include <hip/hip_runtime.h>

// Sinkhorn fixed-point for fermionic canonical ensembles.
// B=2048 systems, P=64 orbitals, N_PART=32, n_iters from d_in[2].
//
// R5 = R4 (passed, absmax 1.17e-2, 152us) with one change class: IEEE '/'
// -> NR-refined reciprocal divides (~1 ulp). Evidence from R0..R4: the
// 20-iter map is ulp-chaotic (op-identical kernels drew 0.0078 vs 0.0234),
// faithful transcendentals + numpy-ordered sums keep the noise floor at the
// fp32-trajectory level (R4 drew 0.0117 vs threshold 0.0214). ~1-ulp divides
// stay in that noise class while cutting the dominant cost: 95 divides/iter
// at ~10 instr / ~45-cyc chain -> 4 instr / ~25-cyc. The aux recursion's 32
// on-chain divides become off-chain parallel muls by invQ[k] (chain collapses
// to mul+sub per step). Everything else is bit-identical to R4:
//   * contract(off), Cody-Waite exp/log, numpy pairwise-sum order
//   * register-shuffle cross-lane only: NO LDS, NO barriers
//   * lane-pipelined Q sweep (lane l carries M=l+1)

#pragma clang fp contract(off)

#define NPART 32
#define PORB  64

#define L2E_HI 1.44269502162933349609375f
#define L2E_LO 1.9259629911266175e-08f
#define LN2_HI 0.69314718246459960938f
#define LN2_LO -1.9046542121259175e-09f
#define LN2F   0.6931471805599453f

__device__ __forceinline__ float readlane_f(float v, int srclane) {
    return __int_as_float(__builtin_amdgcn_readlane(__float_as_int(v), srclane));
}

// reciprocal: v_rcp_f32 + one Newton step => ~0.5-1 ulp
__device__ __forceinline__ float rcp_nr(float d) {
    float r = __builtin_amdgcn_rcpf(d);
    float e = fmaf(-d, r, 1.0f);
    return fmaf(r, e, r);
}

// e^arg with Cody-Waite correction (<=1.5 ulp), arg pre-rounded like numpy
__device__ __forceinline__ float exp_acc(float arg) {
    float p    = arg * L2E_HI;
    float perr = fmaf(arg, L2E_HI, -p);
    float c    = fmaf(arg, L2E_LO, perr);
    float e0   = __builtin_amdgcn_exp2f(p);
    return fmaf(e0, c * LN2F, e0);
}

// ln(x) = log2(x)*ln2 with split constant (~1.5 ulp)
__device__ __forceinline__ float ln_acc(float x) {
    float l2 = __log2f(x);
    float p  = l2 * LN2_HI;
    float e  = fmaf(l2, LN2_HI, -p);
    return p + fmaf(l2, LN2_LO, e);
}

// numpy pairwise_sum order for 64 elements (identical to R4)
__device__ __forceinline__ float pairwise_np(float v, int lane) {
    float c = v;
    #pragma unroll
    for (int i = 1; i < 8; ++i)
        c = c + __shfl(v, (lane + 8 * i) & 63);
    float r0 = readlane_f(c, 0), r1 = readlane_f(c, 1);
    float r2 = readlane_f(c, 2), r3 = readlane_f(c, 3);
    float r4 = readlane_f(c, 4), r5 = readlane_f(c, 5);
    float r6 = readlane_f(c, 6), r7 = readlane_f(c, 7);
    return ((r0 + r1) + (r2 + r3)) + ((r4 + r5) + (r6 + r7));
}

__global__ __launch_bounds__(PORB, 1) void sinkhorn_kernel(
    const float* __restrict__ n_in,
    const float* __restrict__ beta_ptr,
    const int*   __restrict__ iters_ptr,
    float*       __restrict__ out)
{
    const int b    = blockIdx.x;
    const int lane = threadIdx.x;               // orbital index p
    const float beta    = beta_ptr[0];
    const int   n_iters = iters_ptr[0];
    const float nb      = -beta;
    const float inv_beta = rcp_nr(beta);        // beta=1.0 at runtime: exact

    const float n_p = n_in[b * PORB + lane];

    // ---- setup: nn, snn, ratio, eps0 ----
    const float srt = pairwise_np(n_p, lane);
    const float nn  = (n_p * rcp_nr(srt)) * (float)NPART;
    const float snn = pairwise_np(nn, lane);
    const float inv_snn  = rcp_nr(snn);
    const float ratio_nn = nn * rcp_nr(1.0f - nn);
    float eps = (-ln_acc(ratio_nn)) * inv_beta; // eps_GC_guess

    // per-lane constants for the C_k block (identical mapping to R4)
    const float kf    = (float)((lane & 31) + 1);
    const float mk    = nb * kf;
    const int   jbase = (lane & 32) >> 3;

    for (int it = 0; it < n_iters; ++it) {
        // ---- C_k = sum_p exp(-beta*k*eps_p), numpy pairwise order ----
        float acc[4];
        #pragma unroll
        for (int jj = 0; jj < 4; ++jj) {
            #pragma unroll
            for (int i = 0; i < 8; ++i) {
                const int idx = jbase + jj + 8 * i;
                const float ej  = __shfl(eps, idx);
                const float arg = mk * ej;
                const float v   = exp_acc(arg);
                acc[jj] = (i == 0) ? v : (acc[jj] + v);
            }
        }
        float shalf = (acc[0] + acc[1]) + (acc[2] + acc[3]);
        float Cfull = shalf + __shfl_xor(shalf, 32);
        // lane i in 0..31 holds C[i+1]

        const float c1 = readlane_f(Cfull, 0);           // C[1]

        // E_np[i] = C[i+1]/C[i] (lane0 junk, never read)
        const float prevC = __shfl(Cfull, (lane - 1) & 63);
        const float E     = Cfull * rcp_nr(prevC);

        // ---- lane-pipelined Q recursion: lane l carries M=l+1 ----
        // invQ[s] = (s+1) * rcp_nr(c1 * p_s)   (exact-int mul off the rcp)
        float invQ[NPART];
        invQ[0] = rcp_nr(c1);
        float p = 1.0f;
        #pragma unroll
        for (int s = 1; s < NPART; ++s) {
            const float Er = __shfl(E, (lane + 1 - s) & 63); // off-chain
            const float d  = Er * invQ[s - 1];
            const float m  = d * p;
            p = 1.0f - m;
            const float ps = readlane_f(p, s);               // VALU, cheap
            invQ[s] = (float)(s + 1) * rcp_nr(c1 * ps);
        }

        // ---- aux: 32-step recursion; x*invQ[k] all off-chain ----
        const float x = exp_acc(nb * eps);
        float g[NPART];
        #pragma unroll
        for (int k = 0; k < NPART; ++k) g[k] = x * invQ[k];  // parallel
        float prev = 1.0f, y30 = 0.0f;
        #pragma unroll
        for (int k = 0; k < NPART; ++k) {
            const float m = g[k] * prev;
            prev = 1.0f - m;                                 // chain: mul+sub
            if (k == NPART - 2) y30 = prev;
        }
        const float Qp1 = prev;                              // ys[N-1]
        const float Qp0 = y30 * invQ[NPART - 1];             // ys[N-2]/Q[N-1]

        // ---- update + normalize ----
        const float q_arg   = (ratio_nn * Qp1) * rcp_nr(Qp0);
        const float eps_new = (-ln_acc(q_arg)) * inv_beta;

        const float W = pairwise_np(nn * eps_new, lane);
        eps = eps_new - (W * inv_snn);
    }

    out[b * PORB + lane] = eps;
}

extern "C" void kernel_launch(void* const* d_in, const int* in_sizes, int n_in,
                              void* d_out, int out_size, void* d_ws, size_t ws_size,
                              hipStream_t stream) {
    const float* n_ptr    = (const float*)d_in[0];
    const float* beta_ptr = (const float*)d_in[1];
    const int*   it_ptr   = (const int*)d_in[2];
    float*       out      = (float*)d_out;

    const int B = in_sizes[0] / PORB;   // 2048 systems
    sinkhorn_kernel<<<B, PORB, 0, stream>>>(n_ptr, beta_ptr, it_ptr, out);
}

// Round 8
// 125.903 us; speedup vs baseline: 1.4257x; 1.0030x over previous
//
#include <hip/hip_runtime.h>

// Sinkhorn fixed-point for fermionic canonical ensembles.
// B=2048 systems, P=64 orbitals, N_PART=32, n_iters from d_in[2].
//
// R7 = R5 (passed, absmax 0.0156, 77us/dispatch) + ONE value-preserving
// change: the 31 E-gather shuffles are hoisted out of the Q-sweep into a
// preload array. With contract(off) and identical op order this is
// BIT-IDENTICAL to R5 (scheduling cannot change fp values) -- R6 taught us
// the accuracy budget is spent (exp-mismatch floor ~0.012 vs threshold
// 0.0214; every value change re-rolls a wide draw). The hoist removes the
// ~50-cyc ds_bpermute from the 31-step carried chain (R5 rocprof: VALUBusy
// 55% at 2 waves/SIMD => chain-stall bound; sweep chain ~100 cyc/step).
// Post-hoist chain/step: mul+mul+sub+readlane+mul+rcp_nr+mul ~ 45 cyc.
// Accuracy posture unchanged from R4/R5: contract(off), Cody-Waite exp/log,
// numpy pairwise-sum order, ~1ulp rcp_nr divides, register shuffles only
// (no LDS, no barriers).

#pragma clang fp contract(off)

#define NPART 32
#define PORB  64

#define L2E_HI 1.44269502162933349609375f
#define L2E_LO 1.9259629911266175e-08f
#define LN2_HI 0.69314718246459960938f
#define LN2_LO -1.9046542121259175e-09f
#define LN2F   0.6931471805599453f

__device__ __forceinline__ float readlane_f(float v, int srclane) {
    return __int_as_float(__builtin_amdgcn_readlane(__float_as_int(v), srclane));
}

// reciprocal: v_rcp_f32 + one Newton step => ~0.5-1 ulp
__device__ __forceinline__ float rcp_nr(float d) {
    float r = __builtin_amdgcn_rcpf(d);
    float e = fmaf(-d, r, 1.0f);
    return fmaf(r, e, r);
}

// e^arg with Cody-Waite correction (<=1.5 ulp), arg pre-rounded like numpy
__device__ __forceinline__ float exp_acc(float arg) {
    float p    = arg * L2E_HI;
    float perr = fmaf(arg, L2E_HI, -p);
    float c    = fmaf(arg, L2E_LO, perr);
    float e0   = __builtin_amdgcn_exp2f(p);
    return fmaf(e0, c * LN2F, e0);
}

// ln(x) = log2(x)*ln2 with split constant (~1.5 ulp)
__device__ __forceinline__ float ln_acc(float x) {
    float l2 = __log2f(x);
    float p  = l2 * LN2_HI;
    float e  = fmaf(l2, LN2_HI, -p);
    return p + fmaf(l2, LN2_LO, e);
}

// numpy pairwise_sum order for 64 elements (identical to R4/R5)
__device__ __forceinline__ float pairwise_np(float v, int lane) {
    float c = v;
    #pragma unroll
    for (int i = 1; i < 8; ++i)
        c = c + __shfl(v, (lane + 8 * i) & 63);
    float r0 = readlane_f(c, 0), r1 = readlane_f(c, 1);
    float r2 = readlane_f(c, 2), r3 = readlane_f(c, 3);
    float r4 = readlane_f(c, 4), r5 = readlane_f(c, 5);
    float r6 = readlane_f(c, 6), r7 = readlane_f(c, 7);
    return ((r0 + r1) + (r2 + r3)) + ((r4 + r5) + (r6 + r7));
}

__global__ __launch_bounds__(PORB, 1) void sinkhorn_kernel(
    const float* __restrict__ n_in,
    const float* __restrict__ beta_ptr,
    const int*   __restrict__ iters_ptr,
    float*       __restrict__ out)
{
    const int b    = blockIdx.x;
    const int lane = threadIdx.x;               // orbital index p
    const float beta    = beta_ptr[0];
    const int   n_iters = iters_ptr[0];
    const float nb      = -beta;
    const float inv_beta = rcp_nr(beta);

    const float n_p = n_in[b * PORB + lane];

    // ---- setup: nn, snn, ratio, eps0 (identical to R5) ----
    const float srt = pairwise_np(n_p, lane);
    const float nn  = (n_p * rcp_nr(srt)) * (float)NPART;
    const float snn = pairwise_np(nn, lane);
    const float inv_snn  = rcp_nr(snn);
    const float ratio_nn = nn * rcp_nr(1.0f - nn);
    float eps = (-ln_acc(ratio_nn)) * inv_beta; // eps_GC_guess

    // per-lane constants for the C_k block
    const float kf    = (float)((lane & 31) + 1);
    const float mk    = nb * kf;
    const int   jbase = (lane & 32) >> 3;

    for (int it = 0; it < n_iters; ++it) {
        // ---- C_k = sum_p exp(-beta*k*eps_p), numpy pairwise order ----
        float acc[4];
        #pragma unroll
        for (int jj = 0; jj < 4; ++jj) {
            #pragma unroll
            for (int i = 0; i < 8; ++i) {
                const int idx = jbase + jj + 8 * i;
                const float ej  = __shfl(eps, idx);
                const float arg = mk * ej;
                const float v   = exp_acc(arg);
                acc[jj] = (i == 0) ? v : (acc[jj] + v);
            }
        }
        float shalf = (acc[0] + acc[1]) + (acc[2] + acc[3]);
        float Cfull = shalf + __shfl_xor(shalf, 32);
        // lane i in 0..31 holds C[i+1]

        const float c1 = readlane_f(Cfull, 0);           // C[1]

        // E_np[i] = C[i+1]/C[i] (lane0 junk, never read)
        const float prevC = __shfl(Cfull, (lane - 1) & 63);
        const float E     = Cfull * rcp_nr(prevC);

        // ---- preload the 31 E-gathers: value-identical to R5's inline
        // shuffles, but the ds_bpermute latency moves OFF the carried chain
        float Er[NPART];
        #pragma unroll
        for (int s = 1; s < NPART; ++s)
            Er[s] = __shfl(E, (lane + 1 - s) & 63);

        // ---- lane-pipelined Q recursion: lane l carries M=l+1 ----
        // invQ[s] = (s+1) * rcp_nr(c1 * ps)   (exact R5 formula/rounding)
        float invQ[NPART];
        invQ[0] = rcp_nr(c1);
        float p = 1.0f;
        #pragma unroll
        for (int s = 1; s < NPART; ++s) {
            const float d  = Er[s] * invQ[s - 1];
            const float m  = d * p;
            p = 1.0f - m;
            const float ps = readlane_f(p, s);
            invQ[s] = (float)(s + 1) * rcp_nr(c1 * ps);
        }

        // ---- aux: 32-step recursion; x*invQ[k] all off-chain (R5) ----
        const float x = exp_acc(nb * eps);
        float g[NPART];
        #pragma unroll
        for (int k = 0; k < NPART; ++k) g[k] = x * invQ[k];  // parallel
        float prev = 1.0f, y30 = 0.0f;
        #pragma unroll
        for (int k = 0; k < NPART; ++k) {
            const float m = g[k] * prev;
            prev = 1.0f - m;                                 // chain: mul+sub
            if (k == NPART - 2) y30 = prev;
        }
        const float Qp1 = prev;                              // ys[N-1]
        const float Qp0 = y30 * invQ[NPART - 1];             // ys[N-2]/Q[N-1]

        // ---- update + normalize (identical to R5) ----
        const float q_arg   = (ratio_nn * Qp1) * rcp_nr(Qp0);
        const float eps_new = (-ln_acc(q_arg)) * inv_beta;

        const float W = pairwise_np(nn * eps_new, lane);
        eps = eps_new - (W * inv_snn);
    }

    out[b * PORB + lane] = eps;
}

extern "C" void kernel_launch(void* const* d_in, const int* in_sizes, int n_in,
                              void* d_out, int out_size, void* d_ws, size_t ws_size,
                              hipStream_t stream) {
    const float* n_ptr    = (const float*)d_in[0];
    const float* beta_ptr = (const float*)d_in[1];
    const int*   it_ptr   = (const int*)d_in[2];
    float*       out      = (float*)d_out;

    const int B = in_sizes[0] / PORB;   // 2048 systems
    sinkhorn_kernel<<<B, PORB, 0, stream>>>(n_ptr, beta_ptr, it_ptr, out);
}

// Round 9
// 117.753 us; speedup vs baseline: 1.5244x; 1.0692x over previous
//
#include <hip/hip_runtime.h>

// Sinkhorn fixed-point for fermionic canonical ensembles.
// B=2048 systems, P=64 orbitals, N_PART=32, n_iters from d_in[2].
//
// R8 = R7 (passed, absmax 0.015625 == R5 bit-identical, 77us) with the
// schedule FORCED, values untouched:
//  * R7 post-mortem: VGPR stayed 56 and time stayed 77us -- the compiler
//    re-sank the hoisted E-gathers into the sweep (pressure heuristic
//    targets 8 waves/SIMD occupancy we can never use: grid = 2048 waves /
//    1024 SIMDs = 2 waves/SIMD, fixed by problem size).
//  * amdgpu_waves_per_eu(2,2): occupancy target = exactly 2 waves/EU ->
//    VGPR budget 256, scheduler stops trading ILP for occupancy.
//  * asm volatile("" : "+v"(Er[s])) pins: empty, value-identical, but the
//    ds_bpermute def cannot move past the pin -> all 31 gathers issue
//    before the sweep; ~100cyc/step latency comes off the carried chain.
// Time model: chain-bound (VALUBusy 55% at 2 waves = 2*2540/9240 exactly);
// sweep chain 31*(bpermute ~100 + arith ~45) dominates. Post-fix chain
// ~2500-3500 cyc/iter vs issue floor 2*2540 ~ 5080 cyc/iter (~42us).
// Accuracy posture unchanged: contract(off), Cody-Waite exp/log, numpy
// pairwise-sum order, ~1ulp rcp_nr, register shuffles only, no LDS.

#pragma clang fp contract(off)

#define NPART 32
#define PORB  64

#define L2E_HI 1.44269502162933349609375f
#define L2E_LO 1.9259629911266175e-08f
#define LN2_HI 0.69314718246459960938f
#define LN2_LO -1.9046542121259175e-09f
#define LN2F   0.6931471805599453f

__device__ __forceinline__ float readlane_f(float v, int srclane) {
    return __int_as_float(__builtin_amdgcn_readlane(__float_as_int(v), srclane));
}

// reciprocal: v_rcp_f32 + one Newton step => ~0.5-1 ulp
__device__ __forceinline__ float rcp_nr(float d) {
    float r = __builtin_amdgcn_rcpf(d);
    float e = fmaf(-d, r, 1.0f);
    return fmaf(r, e, r);
}

// e^arg with Cody-Waite correction (<=1.5 ulp), arg pre-rounded like numpy
__device__ __forceinline__ float exp_acc(float arg) {
    float p    = arg * L2E_HI;
    float perr = fmaf(arg, L2E_HI, -p);
    float c    = fmaf(arg, L2E_LO, perr);
    float e0   = __builtin_amdgcn_exp2f(p);
    return fmaf(e0, c * LN2F, e0);
}

// ln(x) = log2(x)*ln2 with split constant (~1.5 ulp)
__device__ __forceinline__ float ln_acc(float x) {
    float l2 = __log2f(x);
    float p  = l2 * LN2_HI;
    float e  = fmaf(l2, LN2_HI, -p);
    return p + fmaf(l2, LN2_LO, e);
}

// numpy pairwise_sum order for 64 elements (identical to R4/R5/R7)
__device__ __forceinline__ float pairwise_np(float v, int lane) {
    float c = v;
    #pragma unroll
    for (int i = 1; i < 8; ++i)
        c = c + __shfl(v, (lane + 8 * i) & 63);
    float r0 = readlane_f(c, 0), r1 = readlane_f(c, 1);
    float r2 = readlane_f(c, 2), r3 = readlane_f(c, 3);
    float r4 = readlane_f(c, 4), r5 = readlane_f(c, 5);
    float r6 = readlane_f(c, 6), r7 = readlane_f(c, 7);
    return ((r0 + r1) + (r2 + r3)) + ((r4 + r5) + (r6 + r7));
}

__global__ __launch_bounds__(PORB)
__attribute__((amdgpu_waves_per_eu(2, 2)))
void sinkhorn_kernel(
    const float* __restrict__ n_in,
    const float* __restrict__ beta_ptr,
    const int*   __restrict__ iters_ptr,
    float*       __restrict__ out)
{
    const int b    = blockIdx.x;
    const int lane = threadIdx.x;               // orbital index p
    const float beta    = beta_ptr[0];
    const int   n_iters = iters_ptr[0];
    const float nb      = -beta;
    const float inv_beta = rcp_nr(beta);

    const float n_p = n_in[b * PORB + lane];

    // ---- setup: nn, snn, ratio, eps0 (identical to R5/R7) ----
    const float srt = pairwise_np(n_p, lane);
    const float nn  = (n_p * rcp_nr(srt)) * (float)NPART;
    const float snn = pairwise_np(nn, lane);
    const float inv_snn  = rcp_nr(snn);
    const float ratio_nn = nn * rcp_nr(1.0f - nn);
    float eps = (-ln_acc(ratio_nn)) * inv_beta; // eps_GC_guess

    // per-lane constants for the C_k block
    const float kf    = (float)((lane & 31) + 1);
    const float mk    = nb * kf;
    const int   jbase = (lane & 32) >> 3;

    for (int it = 0; it < n_iters; ++it) {
        // ---- C_k = sum_p exp(-beta*k*eps_p), numpy pairwise order ----
        float acc[4];
        #pragma unroll
        for (int jj = 0; jj < 4; ++jj) {
            #pragma unroll
            for (int i = 0; i < 8; ++i) {
                const int idx = jbase + jj + 8 * i;
                const float ej  = __shfl(eps, idx);
                const float arg = mk * ej;
                const float v   = exp_acc(arg);
                acc[jj] = (i == 0) ? v : (acc[jj] + v);
            }
        }
        float shalf = (acc[0] + acc[1]) + (acc[2] + acc[3]);
        float Cfull = shalf + __shfl_xor(shalf, 32);
        // lane i in 0..31 holds C[i+1]

        const float c1 = readlane_f(Cfull, 0);           // C[1]

        // E_np[i] = C[i+1]/C[i] (lane0 junk, never read)
        const float prevC = __shfl(Cfull, (lane - 1) & 63);
        const float E     = Cfull * rcp_nr(prevC);

        // ---- preload the 31 E-gathers and PIN them (value-identical;
        // the pin stops the scheduler from re-sinking the ds_bpermute
        // into the sweep, which is what kept R7 at R5's speed) ----
        float Er[NPART];
        #pragma unroll
        for (int s = 1; s < NPART; ++s) {
            Er[s] = __shfl(E, (lane + 1 - s) & 63);
            asm volatile("" : "+v"(Er[s]));              // schedule pin only
        }

        // ---- lane-pipelined Q recursion: lane l carries M=l+1 ----
        // invQ[s] = (s+1) * rcp_nr(c1 * ps)   (exact R5 formula/rounding)
        float invQ[NPART];
        invQ[0] = rcp_nr(c1);
        float p = 1.0f;
        #pragma unroll
        for (int s = 1; s < NPART; ++s) {
            const float d  = Er[s] * invQ[s - 1];
            const float m  = d * p;
            p = 1.0f - m;
            const float ps = readlane_f(p, s);
            invQ[s] = (float)(s + 1) * rcp_nr(c1 * ps);
        }

        // ---- aux: 32-step recursion; x*invQ[k] all off-chain ----
        const float x = exp_acc(nb * eps);
        float g[NPART];
        #pragma unroll
        for (int k = 0; k < NPART; ++k) g[k] = x * invQ[k];  // parallel
        float prev = 1.0f, y30 = 0.0f;
        #pragma unroll
        for (int k = 0; k < NPART; ++k) {
            const float m = g[k] * prev;
            prev = 1.0f - m;                                 // chain: mul+sub
            if (k == NPART - 2) y30 = prev;
        }
        const float Qp1 = prev;                              // ys[N-1]
        const float Qp0 = y30 * invQ[NPART - 1];             // ys[N-2]/Q[N-1]

        // ---- update + normalize (identical to R5/R7) ----
        const float q_arg   = (ratio_nn * Qp1) * rcp_nr(Qp0);
        const float eps_new = (-ln_acc(q_arg)) * inv_beta;

        const float W = pairwise_np(nn * eps_new, lane);
        eps = eps_new - (W * inv_snn);
    }

    out[b * PORB + lane] = eps;
}

extern "C" void kernel_launch(void* const* d_in, const int* in_sizes, int n_in,
                              void* d_out, int out_size, void* d_ws, size_t ws_size,
                              hipStream_t stream) {
    const float* n_ptr    = (const float*)d_in[0];
    const float* beta_ptr = (const float*)d_in[1];
    const int*   it_ptr   = (const int*)d_in[2];
    float*       out      = (float*)d_out;

    const int B = in_sizes[0] / PORB;   // 2048 systems
    sinkhorn_kernel<<<B, PORB, 0, stream>>>(n_ptr, beta_ptr, it_ptr, out);
}